// Round 1
// baseline (515.201 us; speedup 1.0000x reference)
//
#include <hip/hip_runtime.h>

#define HW 16384
#define CC 192
#define BB 8
#define NHD 4
#define HD 48

typedef __attribute__((ext_vector_type(8))) short  short8;
typedef __attribute__((ext_vector_type(4))) float  f32x4;

static __device__ __forceinline__ unsigned short f2bf(float f) {
  unsigned u = __float_as_uint(f);
  u += 0x7fffu + ((u >> 16) & 1u);          // round-to-nearest-even
  return (unsigned short)(u >> 16);
}

// MODE 0: q-proj (fp32 in, W fp32, +bias, l2norm per head, bf16 out)
// MODE 1: k-proj (same, W=Wkv rows 0..191)
// MODE 2: v-proj (no norm, bf16 out)
// MODE 3: final  (bf16 V in, per-batch bf16 M, +bp, fp32 out)
template<int MODE>
__global__ __launch_bounds__(256) void proj_kernel(
    const void* __restrict__ xin,
    const void* __restrict__ wsrc,
    const float* __restrict__ bias,
    void* __restrict__ outp)
{
  const int tid  = threadIdx.x;
  const int lane = tid & 63;
  const int wv   = tid >> 6;          // wave 0..3 owns rows [48w,48w+48) = one head
  const int b    = blockIdx.y;
  const int p0   = blockIdx.x * 256;  // 256 positions per block
  const int l15  = lane & 15;
  const int lg   = lane >> 4;

  __shared__ unsigned short Xt[64][200];  // 64 pos x (192+8 pad) bf16, 25.6 KB

  // ---- hoist all A fragments (weights) for this wave's 48 rows, K=192 ----
  short8 afr[6][3];
  if (MODE < 3) {
    const float* W = (const float*)wsrc;
    #pragma unroll
    for (int kk = 0; kk < 6; ++kk) {
      #pragma unroll
      for (int mt = 0; mt < 3; ++mt) {
        const int row = wv*48 + mt*16 + l15;
        const int k0  = kk*32 + lg*8;
        const float* wp = W + row*CC + k0;
        f32x4 w0 = *(const f32x4*)(wp);
        f32x4 w1 = *(const f32x4*)(wp + 4);
        short8 a;
        a[0] = (short)f2bf(w0[0]); a[1] = (short)f2bf(w0[1]);
        a[2] = (short)f2bf(w0[2]); a[3] = (short)f2bf(w0[3]);
        a[4] = (short)f2bf(w1[0]); a[5] = (short)f2bf(w1[1]);
        a[6] = (short)f2bf(w1[2]); a[7] = (short)f2bf(w1[3]);
        afr[kk][mt] = a;
      }
    }
  } else {
    const unsigned short* Mb = (const unsigned short*)wsrc + (size_t)b*CC*CC;
    #pragma unroll
    for (int kk = 0; kk < 6; ++kk)
      #pragma unroll
      for (int mt = 0; mt < 3; ++mt) {
        const int row = wv*48 + mt*16 + l15;
        const int k0  = kk*32 + lg*8;
        afr[kk][mt] = *(const short8*)(Mb + row*CC + k0);
      }
  }

  for (int st = 0; st < 4; ++st) {
    const int pb = p0 + st*64;
    __syncthreads();
    // ---- stage x tile transposed into LDS (coalesced reads along p) ----
    #pragma unroll
    for (int i = 0; i < 24; ++i) {
      const int pi = tid + i*256;       // 0..6143 over (p, channel-pair)
      const int p  = pi & 63;
      const int c0 = (pi >> 6) * 2;
      unsigned short u0, u1;
      if (MODE < 3) {
        const float* X = (const float*)xin + (size_t)b*CC*HW;
        u0 = f2bf(X[(size_t)c0*HW + pb + p]);
        u1 = f2bf(X[(size_t)(c0+1)*HW + pb + p]);
      } else {
        const unsigned short* X = (const unsigned short*)xin + (size_t)b*CC*HW;
        u0 = X[(size_t)c0*HW + pb + p];
        u1 = X[(size_t)(c0+1)*HW + pb + p];
      }
      *(unsigned int*)&Xt[p][c0] = (unsigned)u0 | ((unsigned)u1 << 16);
    }
    __syncthreads();

    f32x4 acc[3][4];
    #pragma unroll
    for (int mt = 0; mt < 3; ++mt)
      #pragma unroll
      for (int nt = 0; nt < 4; ++nt)
        acc[mt][nt] = (f32x4){0.f, 0.f, 0.f, 0.f};

    #pragma unroll
    for (int kk = 0; kk < 6; ++kk) {
      short8 bfr[4];
      #pragma unroll
      for (int nt = 0; nt < 4; ++nt)
        bfr[nt] = *(const short8*)&Xt[nt*16 + l15][kk*32 + lg*8];
      #pragma unroll
      for (int mt = 0; mt < 3; ++mt)
        #pragma unroll
        for (int nt = 0; nt < 4; ++nt)
          acc[mt][nt] = __builtin_amdgcn_mfma_f32_16x16x32_bf16(
              afr[kk][mt], bfr[nt], acc[mt][nt], 0, 0, 0);
    }

    float bv[3][4];
    #pragma unroll
    for (int mt = 0; mt < 3; ++mt)
      #pragma unroll
      for (int r = 0; r < 4; ++r)
        bv[mt][r] = bias[wv*48 + mt*16 + lg*4 + r];

    #pragma unroll
    for (int nt = 0; nt < 4; ++nt) {
      float v[3][4];
      float ss = 0.f;
      #pragma unroll
      for (int mt = 0; mt < 3; ++mt)
        #pragma unroll
        for (int r = 0; r < 4; ++r) {
          const float x = acc[mt][nt][r] + bv[mt][r];
          v[mt][r] = x;
          ss += x*x;
        }
      if (MODE == 0 || MODE == 1) {
        // 48-row (one head) sum of squares for this column: 12 in-lane values
        // + reduce across the 4 lane-groups (same col, different rows)
        ss += __shfl_xor(ss, 16);
        ss += __shfl_xor(ss, 32);
        const float rn = 1.0f / fmaxf(sqrtf(ss), 1e-12f);
        #pragma unroll
        for (int mt = 0; mt < 3; ++mt)
          #pragma unroll
          for (int r = 0; r < 4; ++r)
            v[mt][r] *= rn;
      }
      const int col = pb + nt*16 + l15;
      if (MODE == 3) {
        float* O = (float*)outp + (size_t)b*CC*HW;
        #pragma unroll
        for (int mt = 0; mt < 3; ++mt)
          #pragma unroll
          for (int r = 0; r < 4; ++r)
            O[(size_t)(wv*48 + mt*16 + lg*4 + r)*HW + col] = v[mt][r];
      } else {
        unsigned short* O = (unsigned short*)outp + (size_t)b*CC*HW;
        #pragma unroll
        for (int mt = 0; mt < 3; ++mt)
          #pragma unroll
          for (int r = 0; r < 4; ++r)
            O[(size_t)(wv*48 + mt*16 + lg*4 + r)*HW + col] = f2bf(v[mt][r]);
      }
    }
  }
}

// Gram: G[b,h,c,k] = sum_p qn[c,p]*kn[k,p]; K-split 32-way, partials to ws.
__global__ __launch_bounds__(256) void gram_kernel(
    const unsigned short* __restrict__ Qn,
    const unsigned short* __restrict__ Kn,
    float* __restrict__ Gpart)
{
  const int tid  = threadIdx.x;
  const int lane = tid & 63;
  const int wv   = tid >> 6;
  const int ks   = blockIdx.x;   // 0..7
  const int h    = blockIdx.y;   // 0..3
  const int b    = blockIdx.z;   // 0..7
  const int l15  = lane & 15;
  const int lg   = lane >> 4;

  const unsigned short* Qb = Qn + ((size_t)b*CC + h*HD)*HW;
  const unsigned short* Kb = Kn + ((size_t)b*CC + h*HD)*HW;
  const int pbase = ks*2048 + wv*512;

  f32x4 acc[3][3];
  #pragma unroll
  for (int mt = 0; mt < 3; ++mt)
    #pragma unroll
    for (int nt = 0; nt < 3; ++nt)
      acc[mt][nt] = (f32x4){0.f, 0.f, 0.f, 0.f};

  for (int it = 0; it < 16; ++it) {
    const int p = pbase + it*32 + lg*8;
    short8 a[3], bb[3];
    #pragma unroll
    for (int mt = 0; mt < 3; ++mt)
      a[mt] = *(const short8*)(Qb + (size_t)(mt*16 + l15)*HW + p);
    #pragma unroll
    for (int nt = 0; nt < 3; ++nt)
      bb[nt] = *(const short8*)(Kb + (size_t)(nt*16 + l15)*HW + p);
    #pragma unroll
    for (int mt = 0; mt < 3; ++mt)
      #pragma unroll
      for (int nt = 0; nt < 3; ++nt)
        acc[mt][nt] = __builtin_amdgcn_mfma_f32_16x16x32_bf16(
            a[mt], bb[nt], acc[mt][nt], 0, 0, 0);
  }

  const int slot = ks*4 + wv;     // 0..31
  float* G = Gpart + ((size_t)(b*NHD + h)*32 + slot)*2304;
  #pragma unroll
  for (int mt = 0; mt < 3; ++mt)
    #pragma unroll
    for (int nt = 0; nt < 3; ++nt)
      #pragma unroll
      for (int r = 0; r < 4; ++r)
        G[(mt*16 + lg*4 + r)*HD + nt*16 + l15] = acc[mt][nt][r];
}

// Per batch: reduce Gram partials, softmax(scale*G) rows, M_b = Wp @ BD(attn).
__global__ __launch_bounds__(256) void softmax_m_kernel(
    const float* __restrict__ Gpart,
    const float* __restrict__ Wp,
    const float* __restrict__ temp,
    unsigned short* __restrict__ Mb)
{
  __shared__ float att[NHD][HD][HD];   // 36.9 KB
  const int tid = threadIdx.x;
  const int b   = blockIdx.x;

  for (int e = tid; e < NHD*HD*HD; e += 256) {
    const int h = e / (HD*HD), rc = e % (HD*HD);
    const float* src = Gpart + ((size_t)(b*NHD + h)*32)*2304 + rc;
    float s = 0.f;
    #pragma unroll
    for (int k = 0; k < 32; ++k) s += src[(size_t)k*2304];
    ((float*)att)[e] = s;
  }
  __syncthreads();

  if (tid < CC) {
    const int h = tid / HD, c = tid % HD;
    const float t = temp[h];
    const float scale = 0.1f * (1.0f / (1.0f + expf(-t)));
    float* row = &att[h][c][0];
    float m = -1e30f;
    for (int k = 0; k < HD; ++k) m = fmaxf(m, row[k]*scale);
    float s = 0.f;
    for (int k = 0; k < HD; ++k) { float e = expf(row[k]*scale - m); row[k] = e; s += e; }
    const float inv = 1.0f / s;
    for (int k = 0; k < HD; ++k) row[k] *= inv;
  }
  __syncthreads();

  for (int idx = tid; idx < CC*CC; idx += 256) {
    const int o = idx / CC, j = idx % CC;
    const int h = j / HD, k = j % HD;
    const float* wrow = Wp + o*CC + h*HD;
    float s = 0.f;
    #pragma unroll
    for (int c = 0; c < HD; ++c) s += wrow[c] * att[h][c][k];
    Mb[(size_t)b*CC*CC + idx] = f2bf(s);
  }
}

extern "C" void kernel_launch(void* const* d_in, const int* in_sizes, int n_in,
                              void* d_out, int out_size, void* d_ws, size_t ws_size,
                              hipStream_t stream)
{
  (void)in_sizes; (void)n_in; (void)out_size; (void)ws_size;
  const float* x_q  = (const float*)d_in[0];
  const float* x_k  = (const float*)d_in[1];
  const float* Wq   = (const float*)d_in[2];
  const float* bq   = (const float*)d_in[3];
  const float* Wkv  = (const float*)d_in[4];
  const float* bkv  = (const float*)d_in[5];
  const float* Wp   = (const float*)d_in[6];
  const float* bp   = (const float*)d_in[7];
  const float* temp = (const float*)d_in[8];

  const size_t SQ = (size_t)BB*CC*HW;  // elements per bf16 tensor
  unsigned short* qn = (unsigned short*)d_ws;
  unsigned short* kn = qn + SQ;
  unsigned short* vv = kn + SQ;
  float* gpart = (float*)((char*)d_ws + 3*SQ*sizeof(unsigned short));
  unsigned short* mb = (unsigned short*)((char*)d_ws + 3*SQ*sizeof(unsigned short)
                                         + (size_t)BB*NHD*32*2304*sizeof(float));

  dim3 pgrid(HW/256, BB);
  proj_kernel<0><<<pgrid, 256, 0, stream>>>(x_q, Wq, bq, qn);
  proj_kernel<1><<<pgrid, 256, 0, stream>>>(x_k, Wkv, bkv, kn);
  proj_kernel<2><<<pgrid, 256, 0, stream>>>(x_k, Wkv + CC*CC, bkv + CC, vv);
  gram_kernel<<<dim3(8, NHD, BB), 256, 0, stream>>>(qn, kn, gpart);
  softmax_m_kernel<<<dim3(BB), 256, 0, stream>>>(gpart, Wp, temp, mb);
  proj_kernel<3><<<pgrid, 256, 0, stream>>>(vv, mb, bp, (float*)d_out);
}

// Round 2
// 262.187 us; speedup vs baseline: 1.9650x; 1.9650x over previous
//
#include <hip/hip_runtime.h>

#define HW 16384
#define CC 192
#define BB 8
#define NHD 4
#define HD 48

typedef __attribute__((ext_vector_type(8))) short  short8;
typedef __attribute__((ext_vector_type(4))) float  f32x4;

static __device__ __forceinline__ unsigned short f2bf(float f) {
  unsigned u = __float_as_uint(f);
  u += 0x7fffu + ((u >> 16) & 1u);          // round-to-nearest-even
  return (unsigned short)(u >> 16);
}

// MODE 0: q-proj (fp32 in, W fp32, +bias, l2norm per head, bf16 out)
// MODE 3: final  (bf16 V in, per-batch bf16 M, +bp, fp32 out)
template<int MODE>
__global__ __launch_bounds__(256) void proj_kernel(
    const void* __restrict__ xin,
    const void* __restrict__ wsrc,
    const float* __restrict__ bias,
    void* __restrict__ outp)
{
  const int tid  = threadIdx.x;
  const int lane = tid & 63;
  const int wv   = tid >> 6;          // wave 0..3 owns rows [48w,48w+48) = one head
  const int b    = blockIdx.y;
  const int p0   = blockIdx.x * 256;  // 256 positions per block
  const int l15  = lane & 15;
  const int lg   = lane >> 4;

  __shared__ unsigned short Xt[64][200];  // 64 pos x (192+8 pad) bf16, 25.6 KB

  // ---- hoist all A fragments (weights) for this wave's 48 rows, K=192 ----
  short8 afr[6][3];
  if (MODE < 3) {
    const float* W = (const float*)wsrc;
    #pragma unroll
    for (int kk = 0; kk < 6; ++kk) {
      #pragma unroll
      for (int mt = 0; mt < 3; ++mt) {
        const int row = wv*48 + mt*16 + l15;
        const int k0  = kk*32 + lg*8;
        const float* wp = W + row*CC + k0;
        f32x4 w0 = *(const f32x4*)(wp);
        f32x4 w1 = *(const f32x4*)(wp + 4);
        short8 a;
        a[0] = (short)f2bf(w0[0]); a[1] = (short)f2bf(w0[1]);
        a[2] = (short)f2bf(w0[2]); a[3] = (short)f2bf(w0[3]);
        a[4] = (short)f2bf(w1[0]); a[5] = (short)f2bf(w1[1]);
        a[6] = (short)f2bf(w1[2]); a[7] = (short)f2bf(w1[3]);
        afr[kk][mt] = a;
      }
    }
  } else {
    const unsigned short* Mb = (const unsigned short*)wsrc + (size_t)b*CC*CC;
    #pragma unroll
    for (int kk = 0; kk < 6; ++kk)
      #pragma unroll
      for (int mt = 0; mt < 3; ++mt) {
        const int row = wv*48 + mt*16 + l15;
        const int k0  = kk*32 + lg*8;
        afr[kk][mt] = *(const short8*)(Mb + row*CC + k0);
      }
  }

  for (int st = 0; st < 4; ++st) {
    const int pb = p0 + st*64;
    __syncthreads();
    // ---- stage x tile transposed into LDS (coalesced reads along p) ----
    #pragma unroll
    for (int i = 0; i < 24; ++i) {
      const int pi = tid + i*256;       // 0..6143 over (p, channel-pair)
      const int p  = pi & 63;
      const int c0 = (pi >> 6) * 2;
      unsigned short u0, u1;
      if (MODE < 3) {
        const float* X = (const float*)xin + (size_t)b*CC*HW;
        u0 = f2bf(X[(size_t)c0*HW + pb + p]);
        u1 = f2bf(X[(size_t)(c0+1)*HW + pb + p]);
      } else {
        const unsigned short* X = (const unsigned short*)xin + (size_t)b*CC*HW;
        u0 = X[(size_t)c0*HW + pb + p];
        u1 = X[(size_t)(c0+1)*HW + pb + p];
      }
      *(unsigned int*)&Xt[p][c0] = (unsigned)u0 | ((unsigned)u1 << 16);
    }
    __syncthreads();

    f32x4 acc[3][4];
    #pragma unroll
    for (int mt = 0; mt < 3; ++mt)
      #pragma unroll
      for (int nt = 0; nt < 4; ++nt)
        acc[mt][nt] = (f32x4){0.f, 0.f, 0.f, 0.f};

    #pragma unroll
    for (int kk = 0; kk < 6; ++kk) {
      short8 bfr[4];
      #pragma unroll
      for (int nt = 0; nt < 4; ++nt)
        bfr[nt] = *(const short8*)&Xt[nt*16 + l15][kk*32 + lg*8];
      #pragma unroll
      for (int mt = 0; mt < 3; ++mt)
        #pragma unroll
        for (int nt = 0; nt < 4; ++nt)
          acc[mt][nt] = __builtin_amdgcn_mfma_f32_16x16x32_bf16(
              afr[kk][mt], bfr[nt], acc[mt][nt], 0, 0, 0);
    }

    float bv[3][4];
    #pragma unroll
    for (int mt = 0; mt < 3; ++mt)
      #pragma unroll
      for (int r = 0; r < 4; ++r)
        bv[mt][r] = bias[wv*48 + mt*16 + lg*4 + r];

    #pragma unroll
    for (int nt = 0; nt < 4; ++nt) {
      float v[3][4];
      float ss = 0.f;
      #pragma unroll
      for (int mt = 0; mt < 3; ++mt)
        #pragma unroll
        for (int r = 0; r < 4; ++r) {
          const float x = acc[mt][nt][r] + bv[mt][r];
          v[mt][r] = x;
          ss += x*x;
        }
      if (MODE == 0) {
        ss += __shfl_xor(ss, 16);
        ss += __shfl_xor(ss, 32);
        const float rn = 1.0f / fmaxf(sqrtf(ss), 1e-12f);
        #pragma unroll
        for (int mt = 0; mt < 3; ++mt)
          #pragma unroll
          for (int r = 0; r < 4; ++r)
            v[mt][r] *= rn;
      }
      const int col = pb + nt*16 + l15;
      if (MODE == 3) {
        float* O = (float*)outp + (size_t)b*CC*HW;
        #pragma unroll
        for (int mt = 0; mt < 3; ++mt)
          #pragma unroll
          for (int r = 0; r < 4; ++r)
            O[(size_t)(wv*48 + mt*16 + lg*4 + r)*HW + col] = v[mt][r];
      } else {
        unsigned short* O = (unsigned short*)outp + (size_t)b*CC*HW;
        #pragma unroll
        for (int mt = 0; mt < 3; ++mt)
          #pragma unroll
          for (int r = 0; r < 4; ++r)
            O[(size_t)(wv*48 + mt*16 + lg*4 + r)*HW + col] = f2bf(v[mt][r]);
      }
    }
  }
}

// Fused K+V projection: waves 0-3 = K rows (head wv, L2-normed),
// waves 4-7 = V rows (head wv-4, no norm). x_k read once.
__global__ __launch_bounds__(512) void kv_kernel(
    const float* __restrict__ xin,
    const float* __restrict__ Wkv,
    const float* __restrict__ bkv,
    unsigned short* __restrict__ kout,
    unsigned short* __restrict__ vout)
{
  const int tid  = threadIdx.x;
  const int lane = tid & 63;
  const int wv   = tid >> 6;          // 0..7
  const int isV  = wv >> 2;
  const int hh   = wv & 3;
  const int b    = blockIdx.y;
  const int p0   = blockIdx.x * 256;
  const int l15  = lane & 15;
  const int lg   = lane >> 4;

  __shared__ unsigned short Xt[64][200];

  short8 afr[6][3];
  #pragma unroll
  for (int kk = 0; kk < 6; ++kk)
    #pragma unroll
    for (int mt = 0; mt < 3; ++mt) {
      const int row = isV*CC + hh*48 + mt*16 + l15;
      const int k0  = kk*32 + lg*8;
      const float* wp = Wkv + (size_t)row*CC + k0;
      f32x4 w0 = *(const f32x4*)(wp);
      f32x4 w1 = *(const f32x4*)(wp + 4);
      short8 a;
      a[0] = (short)f2bf(w0[0]); a[1] = (short)f2bf(w0[1]);
      a[2] = (short)f2bf(w0[2]); a[3] = (short)f2bf(w0[3]);
      a[4] = (short)f2bf(w1[0]); a[5] = (short)f2bf(w1[1]);
      a[6] = (short)f2bf(w1[2]); a[7] = (short)f2bf(w1[3]);
      afr[kk][mt] = a;
    }

  const float* X = xin + (size_t)b*CC*HW;
  unsigned short* O = (isV ? vout : kout) + (size_t)b*CC*HW;

  for (int st = 0; st < 4; ++st) {
    const int pb = p0 + st*64;
    __syncthreads();
    #pragma unroll
    for (int i = 0; i < 12; ++i) {
      const int pi = tid + i*512;
      const int p  = pi & 63;
      const int c0 = (pi >> 6) * 2;
      const unsigned short u0 = f2bf(X[(size_t)c0*HW + pb + p]);
      const unsigned short u1 = f2bf(X[(size_t)(c0+1)*HW + pb + p]);
      *(unsigned int*)&Xt[p][c0] = (unsigned)u0 | ((unsigned)u1 << 16);
    }
    __syncthreads();

    f32x4 acc[3][4];
    #pragma unroll
    for (int mt = 0; mt < 3; ++mt)
      #pragma unroll
      for (int nt = 0; nt < 4; ++nt)
        acc[mt][nt] = (f32x4){0.f, 0.f, 0.f, 0.f};

    #pragma unroll
    for (int kk = 0; kk < 6; ++kk) {
      short8 bfr[4];
      #pragma unroll
      for (int nt = 0; nt < 4; ++nt)
        bfr[nt] = *(const short8*)&Xt[nt*16 + l15][kk*32 + lg*8];
      #pragma unroll
      for (int mt = 0; mt < 3; ++mt)
        #pragma unroll
        for (int nt = 0; nt < 4; ++nt)
          acc[mt][nt] = __builtin_amdgcn_mfma_f32_16x16x32_bf16(
              afr[kk][mt], bfr[nt], acc[mt][nt], 0, 0, 0);
    }

    float bv[3][4];
    #pragma unroll
    for (int mt = 0; mt < 3; ++mt)
      #pragma unroll
      for (int r = 0; r < 4; ++r)
        bv[mt][r] = bkv[isV*CC + hh*48 + mt*16 + lg*4 + r];

    #pragma unroll
    for (int nt = 0; nt < 4; ++nt) {
      float v[3][4];
      float ss = 0.f;
      #pragma unroll
      for (int mt = 0; mt < 3; ++mt)
        #pragma unroll
        for (int r = 0; r < 4; ++r) {
          const float x = acc[mt][nt][r] + bv[mt][r];
          v[mt][r] = x;
          ss += x*x;
        }
      if (!isV) {                       // wave-uniform branch
        ss += __shfl_xor(ss, 16);
        ss += __shfl_xor(ss, 32);
        const float rn = 1.0f / fmaxf(sqrtf(ss), 1e-12f);
        #pragma unroll
        for (int mt = 0; mt < 3; ++mt)
          #pragma unroll
          for (int r = 0; r < 4; ++r)
            v[mt][r] *= rn;
      }
      const int col = pb + nt*16 + l15;
      #pragma unroll
      for (int mt = 0; mt < 3; ++mt)
        #pragma unroll
        for (int r = 0; r < 4; ++r)
          O[(size_t)(hh*48 + mt*16 + lg*4 + r)*HW + col] = f2bf(v[mt][r]);
    }
  }
}

// Gram: G[b,h,c,k] = sum_p qn[c,p]*kn[k,p]; K-split 32-way, partials to ws.
__global__ __launch_bounds__(256) void gram_kernel(
    const unsigned short* __restrict__ Qn,
    const unsigned short* __restrict__ Kn,
    float* __restrict__ Gpart)
{
  const int tid  = threadIdx.x;
  const int lane = tid & 63;
  const int wv   = tid >> 6;
  const int ks   = blockIdx.x;   // 0..7
  const int h    = blockIdx.y;   // 0..3
  const int b    = blockIdx.z;   // 0..7
  const int l15  = lane & 15;
  const int lg   = lane >> 4;

  const unsigned short* Qb = Qn + ((size_t)b*CC + h*HD)*HW;
  const unsigned short* Kb = Kn + ((size_t)b*CC + h*HD)*HW;
  const int pbase = ks*2048 + wv*512;

  f32x4 acc[3][3];
  #pragma unroll
  for (int mt = 0; mt < 3; ++mt)
    #pragma unroll
    for (int nt = 0; nt < 3; ++nt)
      acc[mt][nt] = (f32x4){0.f, 0.f, 0.f, 0.f};

  for (int it = 0; it < 16; ++it) {
    const int p = pbase + it*32 + lg*8;
    short8 a[3], bb[3];
    #pragma unroll
    for (int mt = 0; mt < 3; ++mt)
      a[mt] = *(const short8*)(Qb + (size_t)(mt*16 + l15)*HW + p);
    #pragma unroll
    for (int nt = 0; nt < 3; ++nt)
      bb[nt] = *(const short8*)(Kb + (size_t)(nt*16 + l15)*HW + p);
    #pragma unroll
    for (int mt = 0; mt < 3; ++mt)
      #pragma unroll
      for (int nt = 0; nt < 3; ++nt)
        acc[mt][nt] = __builtin_amdgcn_mfma_f32_16x16x32_bf16(
            a[mt], bb[nt], acc[mt][nt], 0, 0, 0);
  }

  const int slot = ks*4 + wv;     // 0..31
  float* G = Gpart + ((size_t)(b*NHD + h)*32 + slot)*2304;
  #pragma unroll
  for (int mt = 0; mt < 3; ++mt)
    #pragma unroll
    for (int nt = 0; nt < 3; ++nt)
      #pragma unroll
      for (int r = 0; r < 4; ++r)
        G[(mt*16 + lg*4 + r)*HD + nt*16 + l15] = acc[mt][nt][r];
}

// Per (b,h): reduce Gram partials, wave-parallel row softmax, then
// M_b[o][h*48+k] = sum_c Wp[o][h*48+c] * attn[c][k]  (bf16 out).
__global__ __launch_bounds__(256) void attn_m_kernel(
    const float* __restrict__ Gpart,
    const float* __restrict__ Wp,
    const float* __restrict__ temp,
    unsigned short* __restrict__ Mb)
{
  __shared__ float att[HD][52];        // +4 pad: conflict-light row access
  const int bh  = blockIdx.x;          // 0..31
  const int b   = bh >> 2, h = bh & 3;
  const int tid = threadIdx.x;
  const float* src = Gpart + (size_t)bh*32*2304;

  #pragma unroll
  for (int i = 0; i < 9; ++i) {
    const int e = tid + i*256;         // 2304 = 9*256
    float s = 0.f;
    #pragma unroll
    for (int k = 0; k < 32; ++k) s += src[(size_t)k*2304 + e];
    att[e/48][e%48] = s;
  }
  __syncthreads();

  // softmax: 4 lanes per row, 48 rows handled by threads 0..191
  const int g = tid >> 2, sl = tid & 3;
  if (g < HD) {
    const float t = temp[h];
    const float scale = 0.1f / (1.0f + expf(-t));   // 0.1*sigmoid(t)
    float* row = att[g];
    float m = -1e30f;
    #pragma unroll
    for (int jj = 0; jj < 12; ++jj) m = fmaxf(m, row[sl + jj*4]);
    m = fmaxf(m, __shfl_xor(m, 1));
    m = fmaxf(m, __shfl_xor(m, 2));
    float ev[12];
    float s = 0.f;
    #pragma unroll
    for (int jj = 0; jj < 12; ++jj) {
      const float e = expf((row[sl + jj*4] - m) * scale);
      ev[jj] = e; s += e;
    }
    s += __shfl_xor(s, 1);
    s += __shfl_xor(s, 2);
    const float inv = 1.0f / s;
    #pragma unroll
    for (int jj = 0; jj < 12; ++jj) row[sl + jj*4] = ev[jj] * inv;
  }
  __syncthreads();

  // M block for this (b,h): 192 x 48 outputs, 36 per thread
  #pragma unroll
  for (int i = 0; i < 36; ++i) {
    const int idx = tid + i*256;       // 0..9215
    const int o = idx / HD, k2 = idx % HD;
    const float* wrow = Wp + (size_t)o*CC + h*HD;
    float s = 0.f;
    #pragma unroll
    for (int c = 0; c < HD; ++c) s += wrow[c] * att[c][k2];
    Mb[(size_t)b*CC*CC + (size_t)o*CC + h*HD + k2] = f2bf(s);
  }
}

extern "C" void kernel_launch(void* const* d_in, const int* in_sizes, int n_in,
                              void* d_out, int out_size, void* d_ws, size_t ws_size,
                              hipStream_t stream)
{
  (void)in_sizes; (void)n_in; (void)out_size; (void)ws_size;
  const float* x_q  = (const float*)d_in[0];
  const float* x_k  = (const float*)d_in[1];
  const float* Wq   = (const float*)d_in[2];
  const float* bq   = (const float*)d_in[3];
  const float* Wkv  = (const float*)d_in[4];
  const float* bkv  = (const float*)d_in[5];
  const float* Wp   = (const float*)d_in[6];
  const float* bp   = (const float*)d_in[7];
  const float* temp = (const float*)d_in[8];

  const size_t SQ = (size_t)BB*CC*HW;  // elements per bf16 tensor
  unsigned short* qn = (unsigned short*)d_ws;
  unsigned short* kn = qn + SQ;
  unsigned short* vv = kn + SQ;
  float* gpart = (float*)((char*)d_ws + 3*SQ*sizeof(unsigned short));
  unsigned short* mb = (unsigned short*)((char*)d_ws + 3*SQ*sizeof(unsigned short)
                                         + (size_t)BB*NHD*32*2304*sizeof(float));

  dim3 pgrid(HW/256, BB);
  proj_kernel<0><<<pgrid, 256, 0, stream>>>(x_q, Wq, bq, qn);
  kv_kernel<<<pgrid, 512, 0, stream>>>(x_k, Wkv, bkv, kn, vv);
  gram_kernel<<<dim3(8, NHD, BB), 256, 0, stream>>>(qn, kn, gpart);
  attn_m_kernel<<<dim3(BB*NHD), 256, 0, stream>>>(gpart, Wp, temp, mb);
  proj_kernel<3><<<pgrid, 256, 0, stream>>>(vv, mb, bp, (float*)d_out);
}

// Round 3
// 229.233 us; speedup vs baseline: 2.2475x; 1.1438x over previous
//
#include <hip/hip_runtime.h>

#define HW 16384
#define CC 192
#define BB 8
#define NHD 4
#define HD 48

typedef __attribute__((ext_vector_type(8))) short  short8;
typedef __attribute__((ext_vector_type(4))) float  f32x4;
typedef __attribute__((ext_vector_type(4))) unsigned short us4;

static __device__ __forceinline__ unsigned short f2bf(float f) {
  unsigned u = __float_as_uint(f);
  u += 0x7fffu + ((u >> 16) & 1u);          // round-to-nearest-even
  return (unsigned short)(u >> 16);
}

// Cast Wq (192x192) and Wkv (384x192) fp32 -> bf16 into ws, contiguous.
__global__ __launch_bounds__(256) void cast_w_kernel(
    const float* __restrict__ Wq, const float* __restrict__ Wkv,
    unsigned short* __restrict__ Wb)
{
  const int i = blockIdx.x * 256 + threadIdx.x;   // 0 .. 110591
  const float v = (i < CC*CC) ? Wq[i] : Wkv[i - CC*CC];
  Wb[i] = f2bf(v);
}

// MODE 0: q-proj (fp32 in, bf16 W from ws, +bias, l2norm per head, bf16 out)
// MODE 3: final  (bf16 V in, per-batch bf16 M, +bp, fp32 out)
// 64 positions per block, 4 waves (wave = head).
template<int MODE>
__global__ __launch_bounds__(256) void proj_kernel(
    const void* __restrict__ xin,
    const unsigned short* __restrict__ wsrc,
    const float* __restrict__ bias,
    void* __restrict__ outp)
{
  const int tid  = threadIdx.x;
  const int lane = tid & 63;
  const int wv   = tid >> 6;
  const int b    = blockIdx.y;
  const int p0   = blockIdx.x * 64;
  const int l15  = lane & 15;
  const int lg   = lane >> 4;

  __shared__ unsigned short Xt[64][200];  // 64 pos x (192+8 pad) bf16

  // A fragments: 18 direct bf16 loads (L2-hot)
  const unsigned short* Wb = (MODE == 0) ? wsrc : wsrc + (size_t)b*CC*CC;
  short8 afr[6][3];
  #pragma unroll
  for (int kk = 0; kk < 6; ++kk)
    #pragma unroll
    for (int mt = 0; mt < 3; ++mt)
      afr[kk][mt] = *(const short8*)(Wb + (size_t)(wv*48 + mt*16 + l15)*CC + kk*32 + lg*8);

  // ---- stage 64 x 192 tile (transposed) ----
  if (MODE == 0) {
    const float* X = (const float*)xin + (size_t)b*CC*HW + p0;
    #pragma unroll
    for (int i = 0; i < 6; ++i) {
      const int it = tid + i*256;        // 1536 = 96 ch-pairs x 16 pos-quads
      const int qd = it & 15, cp = it >> 4;
      const f32x4 v0 = *(const f32x4*)(X + (size_t)(2*cp  )*HW + qd*4);
      const f32x4 v1 = *(const f32x4*)(X + (size_t)(2*cp+1)*HW + qd*4);
      #pragma unroll
      for (int j = 0; j < 4; ++j)
        *(unsigned*)&Xt[qd*4 + j][2*cp] =
            (unsigned)f2bf(v0[j]) | ((unsigned)f2bf(v1[j]) << 16);
    }
  } else {
    const unsigned short* X = (const unsigned short*)xin + (size_t)b*CC*HW + p0;
    #pragma unroll
    for (int i = 0; i < 6; ++i) {
      const int it = tid + i*256;
      const int qd = it & 15, cp = it >> 4;
      const us4 a0 = *(const us4*)(X + (size_t)(2*cp  )*HW + qd*4);
      const us4 a1 = *(const us4*)(X + (size_t)(2*cp+1)*HW + qd*4);
      #pragma unroll
      for (int j = 0; j < 4; ++j)
        *(unsigned*)&Xt[qd*4 + j][2*cp] = (unsigned)a0[j] | ((unsigned)a1[j] << 16);
    }
  }
  __syncthreads();

  f32x4 acc[3][4];
  #pragma unroll
  for (int mt = 0; mt < 3; ++mt)
    #pragma unroll
    for (int nt = 0; nt < 4; ++nt)
      acc[mt][nt] = (f32x4){0.f, 0.f, 0.f, 0.f};

  #pragma unroll
  for (int kk = 0; kk < 6; ++kk) {
    short8 bfr[4];
    #pragma unroll
    for (int nt = 0; nt < 4; ++nt)
      bfr[nt] = *(const short8*)&Xt[nt*16 + l15][kk*32 + lg*8];
    #pragma unroll
    for (int mt = 0; mt < 3; ++mt)
      #pragma unroll
      for (int nt = 0; nt < 4; ++nt)
        acc[mt][nt] = __builtin_amdgcn_mfma_f32_16x16x32_bf16(
            afr[kk][mt], bfr[nt], acc[mt][nt], 0, 0, 0);
  }

  float bv[3][4];
  #pragma unroll
  for (int mt = 0; mt < 3; ++mt)
    #pragma unroll
    for (int r = 0; r < 4; ++r)
      bv[mt][r] = bias[wv*48 + mt*16 + lg*4 + r];

  #pragma unroll
  for (int nt = 0; nt < 4; ++nt) {
    float v[3][4];
    float ss = 0.f;
    #pragma unroll
    for (int mt = 0; mt < 3; ++mt)
      #pragma unroll
      for (int r = 0; r < 4; ++r) {
        const float x = acc[mt][nt][r] + bv[mt][r];
        v[mt][r] = x;
        ss += x*x;
      }
    if (MODE == 0) {
      ss += __shfl_xor(ss, 16);
      ss += __shfl_xor(ss, 32);
      const float rn = 1.0f / fmaxf(sqrtf(ss), 1e-12f);
      #pragma unroll
      for (int mt = 0; mt < 3; ++mt)
        #pragma unroll
        for (int r = 0; r < 4; ++r)
          v[mt][r] *= rn;
    }
    const int col = p0 + nt*16 + l15;
    if (MODE == 3) {
      float* O = (float*)outp + (size_t)b*CC*HW;
      #pragma unroll
      for (int mt = 0; mt < 3; ++mt)
        #pragma unroll
        for (int r = 0; r < 4; ++r)
          O[(size_t)(wv*48 + mt*16 + lg*4 + r)*HW + col] = v[mt][r];
    } else {
      unsigned short* O = (unsigned short*)outp + (size_t)b*CC*HW;
      #pragma unroll
      for (int mt = 0; mt < 3; ++mt)
        #pragma unroll
        for (int r = 0; r < 4; ++r)
          O[(size_t)(wv*48 + mt*16 + lg*4 + r)*HW + col] = f2bf(v[mt][r]);
    }
  }
}

// Fused K+V projection: waves 0-3 = K rows (head wv, L2-normed),
// waves 4-7 = V rows (head wv-4). 64 positions per block, 512 threads.
__global__ __launch_bounds__(512) void kv_kernel(
    const float* __restrict__ xin,
    const unsigned short* __restrict__ Wkvb,
    const float* __restrict__ bkv,
    unsigned short* __restrict__ kout,
    unsigned short* __restrict__ vout)
{
  const int tid  = threadIdx.x;
  const int lane = tid & 63;
  const int wv   = tid >> 6;          // 0..7
  const int isV  = wv >> 2;
  const int hh   = wv & 3;
  const int b    = blockIdx.y;
  const int p0   = blockIdx.x * 64;
  const int l15  = lane & 15;
  const int lg   = lane >> 4;

  __shared__ unsigned short Xt[64][200];

  short8 afr[6][3];
  #pragma unroll
  for (int kk = 0; kk < 6; ++kk)
    #pragma unroll
    for (int mt = 0; mt < 3; ++mt)
      afr[kk][mt] = *(const short8*)(Wkvb +
          (size_t)(isV*CC + hh*48 + mt*16 + l15)*CC + kk*32 + lg*8);

  const float* X = xin + (size_t)b*CC*HW + p0;
  #pragma unroll
  for (int i = 0; i < 3; ++i) {
    const int it = tid + i*512;
    const int qd = it & 15, cp = it >> 4;
    const f32x4 v0 = *(const f32x4*)(X + (size_t)(2*cp  )*HW + qd*4);
    const f32x4 v1 = *(const f32x4*)(X + (size_t)(2*cp+1)*HW + qd*4);
    #pragma unroll
    for (int j = 0; j < 4; ++j)
      *(unsigned*)&Xt[qd*4 + j][2*cp] =
          (unsigned)f2bf(v0[j]) | ((unsigned)f2bf(v1[j]) << 16);
  }
  __syncthreads();

  f32x4 acc[3][4];
  #pragma unroll
  for (int mt = 0; mt < 3; ++mt)
    #pragma unroll
    for (int nt = 0; nt < 4; ++nt)
      acc[mt][nt] = (f32x4){0.f, 0.f, 0.f, 0.f};

  #pragma unroll
  for (int kk = 0; kk < 6; ++kk) {
    short8 bfr[4];
    #pragma unroll
    for (int nt = 0; nt < 4; ++nt)
      bfr[nt] = *(const short8*)&Xt[nt*16 + l15][kk*32 + lg*8];
    #pragma unroll
    for (int mt = 0; mt < 3; ++mt)
      #pragma unroll
      for (int nt = 0; nt < 4; ++nt)
        acc[mt][nt] = __builtin_amdgcn_mfma_f32_16x16x32_bf16(
            afr[kk][mt], bfr[nt], acc[mt][nt], 0, 0, 0);
  }

  float bv[3][4];
  #pragma unroll
  for (int mt = 0; mt < 3; ++mt)
    #pragma unroll
    for (int r = 0; r < 4; ++r)
      bv[mt][r] = bkv[isV*CC + hh*48 + mt*16 + lg*4 + r];

  unsigned short* O = (isV ? vout : kout) + (size_t)b*CC*HW;

  #pragma unroll
  for (int nt = 0; nt < 4; ++nt) {
    float v[3][4];
    float ss = 0.f;
    #pragma unroll
    for (int mt = 0; mt < 3; ++mt)
      #pragma unroll
      for (int r = 0; r < 4; ++r) {
        const float x = acc[mt][nt][r] + bv[mt][r];
        v[mt][r] = x;
        ss += x*x;
      }
    if (!isV) {                       // wave-uniform branch
      ss += __shfl_xor(ss, 16);
      ss += __shfl_xor(ss, 32);
      const float rn = 1.0f / fmaxf(sqrtf(ss), 1e-12f);
      #pragma unroll
      for (int mt = 0; mt < 3; ++mt)
        #pragma unroll
        for (int r = 0; r < 4; ++r)
          v[mt][r] *= rn;
    }
    const int col = p0 + nt*16 + l15;
    #pragma unroll
    for (int mt = 0; mt < 3; ++mt)
      #pragma unroll
      for (int r = 0; r < 4; ++r)
        O[(size_t)(hh*48 + mt*16 + lg*4 + r)*HW + col] = f2bf(v[mt][r]);
  }
}

// Gram: G[b,h,c,k] = sum_p qn[c,p]*kn[k,p]; K-split 32-way, partials to ws.
__global__ __launch_bounds__(256) void gram_kernel(
    const unsigned short* __restrict__ Qn,
    const unsigned short* __restrict__ Kn,
    float* __restrict__ Gpart)
{
  const int tid  = threadIdx.x;
  const int lane = tid & 63;
  const int wv   = tid >> 6;
  const int ks   = blockIdx.x;   // 0..7
  const int h    = blockIdx.y;   // 0..3
  const int b    = blockIdx.z;   // 0..7
  const int l15  = lane & 15;
  const int lg   = lane >> 4;

  const unsigned short* Qb = Qn + ((size_t)b*CC + h*HD)*HW;
  const unsigned short* Kb = Kn + ((size_t)b*CC + h*HD)*HW;
  const int pbase = ks*2048 + wv*512;

  f32x4 acc[3][3];
  #pragma unroll
  for (int mt = 0; mt < 3; ++mt)
    #pragma unroll
    for (int nt = 0; nt < 3; ++nt)
      acc[mt][nt] = (f32x4){0.f, 0.f, 0.f, 0.f};

  for (int it = 0; it < 16; ++it) {
    const int p = pbase + it*32 + lg*8;
    short8 a[3], bb[3];
    #pragma unroll
    for (int mt = 0; mt < 3; ++mt)
      a[mt] = *(const short8*)(Qb + (size_t)(mt*16 + l15)*HW + p);
    #pragma unroll
    for (int nt = 0; nt < 3; ++nt)
      bb[nt] = *(const short8*)(Kb + (size_t)(nt*16 + l15)*HW + p);
    #pragma unroll
    for (int mt = 0; mt < 3; ++mt)
      #pragma unroll
      for (int nt = 0; nt < 3; ++nt)
        acc[mt][nt] = __builtin_amdgcn_mfma_f32_16x16x32_bf16(
            a[mt], bb[nt], acc[mt][nt], 0, 0, 0);
  }

  const int slot = ks*4 + wv;     // 0..31
  float* G = Gpart + ((size_t)(b*NHD + h)*32 + slot)*2304;
  #pragma unroll
  for (int mt = 0; mt < 3; ++mt)
    #pragma unroll
    for (int nt = 0; nt < 3; ++nt)
      #pragma unroll
      for (int r = 0; r < 4; ++r)
        G[(mt*16 + lg*4 + r)*HD + nt*16 + l15] = acc[mt][nt][r];
}

// Per (b,h): reduce Gram partials, wave-parallel row softmax, then
// M_b[o][h*48+k] = sum_c Wp[o][h*48+c] * attn[c][k]  (bf16 out).
__global__ __launch_bounds__(256) void attn_m_kernel(
    const float* __restrict__ Gpart,
    const float* __restrict__ Wp,
    const float* __restrict__ temp,
    unsigned short* __restrict__ Mb)
{
  __shared__ float att[HD][52];        // +4 pad
  const int bh  = blockIdx.x;          // 0..31
  const int b   = bh >> 2, h = bh & 3;
  const int tid = threadIdx.x;
  const float* src = Gpart + (size_t)bh*32*2304;

  #pragma unroll
  for (int i = 0; i < 9; ++i) {
    const int e = tid + i*256;         // 2304 = 9*256
    float s = 0.f;
    #pragma unroll
    for (int k = 0; k < 32; ++k) s += src[(size_t)k*2304 + e];
    att[e/48][e%48] = s;
  }
  __syncthreads();

  const int g = tid >> 2, sl = tid & 3;
  if (g < HD) {
    const float t = temp[h];
    const float scale = 0.1f / (1.0f + expf(-t));   // 0.1*sigmoid(t)
    float* row = att[g];
    float m = -1e30f;
    #pragma unroll
    for (int jj = 0; jj < 12; ++jj) m = fmaxf(m, row[sl + jj*4]);
    m = fmaxf(m, __shfl_xor(m, 1));
    m = fmaxf(m, __shfl_xor(m, 2));
    float ev[12];
    float s = 0.f;
    #pragma unroll
    for (int jj = 0; jj < 12; ++jj) {
      const float e = expf((row[sl + jj*4] - m) * scale);
      ev[jj] = e; s += e;
    }
    s += __shfl_xor(s, 1);
    s += __shfl_xor(s, 2);
    const float inv = 1.0f / s;
    #pragma unroll
    for (int jj = 0; jj < 12; ++jj) row[sl + jj*4] = ev[jj] * inv;
  }
  __syncthreads();

  #pragma unroll
  for (int i = 0; i < 36; ++i) {
    const int idx = tid + i*256;       // 0..9215
    const int o = idx / HD, k2 = idx % HD;
    const float* wrow = Wp + (size_t)o*CC + h*HD;
    float s = 0.f;
    #pragma unroll
    for (int c = 0; c < HD; ++c) s += wrow[c] * att[c][k2];
    Mb[(size_t)b*CC*CC + (size_t)o*CC + h*HD + k2] = f2bf(s);
  }
}

extern "C" void kernel_launch(void* const* d_in, const int* in_sizes, int n_in,
                              void* d_out, int out_size, void* d_ws, size_t ws_size,
                              hipStream_t stream)
{
  (void)in_sizes; (void)n_in; (void)out_size; (void)ws_size;
  const float* x_q  = (const float*)d_in[0];
  const float* x_k  = (const float*)d_in[1];
  const float* Wq   = (const float*)d_in[2];
  const float* bq   = (const float*)d_in[3];
  const float* Wkv  = (const float*)d_in[4];
  const float* bkv  = (const float*)d_in[5];
  const float* Wp   = (const float*)d_in[6];
  const float* bp   = (const float*)d_in[7];
  const float* temp = (const float*)d_in[8];

  const size_t SQ = (size_t)BB*CC*HW;  // elements per bf16 tensor
  unsigned short* qn = (unsigned short*)d_ws;
  unsigned short* kn = qn + SQ;
  unsigned short* vv = kn + SQ;
  char* p = (char*)d_ws + 3*SQ*sizeof(unsigned short);
  float* gpart = (float*)p;                    p += (size_t)BB*NHD*32*2304*sizeof(float);
  unsigned short* mb = (unsigned short*)p;     p += (size_t)BB*CC*CC*sizeof(unsigned short);
  unsigned short* wb = (unsigned short*)p;     // 110592 bf16 (Wq | Wkv)

  cast_w_kernel<<<dim3((3*CC*CC)/256), 256, 0, stream>>>(Wq, Wkv, wb);

  dim3 pgrid(HW/64, BB);
  proj_kernel<0><<<pgrid, 256, 0, stream>>>(x_q, wb, bq, qn);
  kv_kernel<<<pgrid, 512, 0, stream>>>(x_k, wb + CC*CC, bkv, kn, vv);
  gram_kernel<<<dim3(8, NHD, BB), 256, 0, stream>>>(qn, kn, gpart);
  attn_m_kernel<<<dim3(BB*NHD), 256, 0, stream>>>(gpart, Wp, temp, mb);
  proj_kernel<3><<<pgrid, 256, 0, stream>>>(vv, mb, bp, (float*)d_out);
}